// Round 1
// baseline (1507.608 us; speedup 1.0000x reference)
//
#include <hip/hip_runtime.h>
#include <hip/hip_bf16.h>

#define Df 384
#define Hf 768

typedef __bf16 bf16x8 __attribute__((ext_vector_type(8)));
typedef float f32x4 __attribute__((ext_vector_type(4)));

__device__ inline unsigned short f2bf(float f) {
    __hip_bfloat16 h = __float2bfloat16(f);
    return __builtin_bit_cast(unsigned short, h);
}
__device__ inline float bf2f(unsigned short u) {
    unsigned int v = ((unsigned int)u) << 16;
    return __builtin_bit_cast(float, v);
}
__device__ inline unsigned int pk2(float a, float b) {
    return (unsigned int)f2bf(a) | ((unsigned int)f2bf(b) << 16);
}
__device__ inline float gelu_(float v) {
    return 0.5f * v * (1.0f + erff(v * 0.70710678118654752f));
}

// ---- BN column statistics: sum + sumsq per feature ----
__global__ void bn_stats(const float* __restrict__ x, float* __restrict__ stats, int N) {
    int t = threadIdx.x;                 // 192 threads
    int c4 = (t % 96) * 4;               // column group (4 floats)
    int rs = t / 96;                     // 0/1 row sub-offset
    float s0 = 0, s1 = 0, s2 = 0, s3 = 0, q0 = 0, q1 = 0, q2 = 0, q3 = 0;
    for (int r = blockIdx.x * 2 + rs; r < N; r += gridDim.x * 2) {
        float4 v = *(const float4*)(x + (size_t)r * Df + c4);
        s0 += v.x; s1 += v.y; s2 += v.z; s3 += v.w;
        q0 += v.x * v.x; q1 += v.y * v.y; q2 += v.z * v.z; q3 += v.w * v.w;
    }
    unsafeAtomicAdd(&stats[c4 + 0], s0);
    unsafeAtomicAdd(&stats[c4 + 1], s1);
    unsafeAtomicAdd(&stats[c4 + 2], s2);
    unsafeAtomicAdd(&stats[c4 + 3], s3);
    unsafeAtomicAdd(&stats[Df + c4 + 0], q0);
    unsafeAtomicAdd(&stats[Df + c4 + 1], q1);
    unsafeAtomicAdd(&stats[Df + c4 + 2], q2);
    unsafeAtomicAdd(&stats[Df + c4 + 3], q3);
}

__global__ void bn_finalize(const float* __restrict__ stats,
                            const float* __restrict__ gamma,
                            const float* __restrict__ beta,
                            float* __restrict__ coef, int N) {
    int c = threadIdx.x; // 384
    float invN = 1.0f / (float)N;
    float mu = stats[c] * invN;
    float var = stats[Df + c] * invN - mu * mu;
    float rs = rsqrtf(var + 1e-5f);
    float a = gamma[c] * rs;
    coef[c] = a;
    coef[Df + c] = beta[c] - mu * a;
}

// ---- h = x*a + b  ->  bf16 ----
__global__ void h_kernel(const float* __restrict__ x, const float* __restrict__ coef,
                         unsigned short* __restrict__ hb, int tot8) {
    int i = blockIdx.x * 256 + threadIdx.x;
    if (i >= tot8) return;
    size_t base = (size_t)i * 8;
    int c = (int)(base % Df);
    float4 x0 = *(const float4*)(x + base);
    float4 x1 = *(const float4*)(x + base + 4);
    const float* a = coef + c;
    const float* b = coef + Df + c;
    uint4 o;
    o.x = pk2(x0.x * a[0] + b[0], x0.y * a[1] + b[1]);
    o.y = pk2(x0.z * a[2] + b[2], x0.w * a[3] + b[3]);
    o.z = pk2(x1.x * a[4] + b[4], x1.y * a[5] + b[5]);
    o.w = pk2(x1.z * a[6] + b[6], x1.w * a[7] + b[7]);
    *(uint4*)(hb + base) = o;
}

// ---- z = (1+eps)*h + agg  -> bf16 ----
__global__ void z_kernel(const unsigned short* __restrict__ hb, const float* __restrict__ agg,
                         const float* __restrict__ epsp, unsigned short* __restrict__ zb, int tot8) {
    int i = blockIdx.x * 256 + threadIdx.x;
    if (i >= tot8) return;
    float s = 1.0f + epsp[0];
    size_t base = (size_t)i * 8;
    uint4 hv = *(const uint4*)(hb + base);
    float4 a0 = *(const float4*)(agg + base);
    float4 a1 = *(const float4*)(agg + base + 4);
    uint4 o;
    o.x = pk2(s * bf2f((unsigned short)(hv.x & 0xffff)) + a0.x,
              s * bf2f((unsigned short)(hv.x >> 16)) + a0.y);
    o.y = pk2(s * bf2f((unsigned short)(hv.y & 0xffff)) + a0.z,
              s * bf2f((unsigned short)(hv.y >> 16)) + a0.w);
    o.z = pk2(s * bf2f((unsigned short)(hv.z & 0xffff)) + a1.x,
              s * bf2f((unsigned short)(hv.z >> 16)) + a1.y);
    o.w = pk2(s * bf2f((unsigned short)(hv.w & 0xffff)) + a1.z,
              s * bf2f((unsigned short)(hv.w >> 16)) + a1.w);
    *(uint4*)(zb + base) = o;
}

// ---- weight transpose + cast: W[K][Nc] f32 -> Wt[Nc][K] bf16 ----
__global__ void wtrans(const float* __restrict__ Wsrc, unsigned short* __restrict__ Wdst,
                       int K, int Nc) {
    int idx = blockIdx.x * 256 + threadIdx.x;
    if (idx >= K * Nc) return;
    int k = idx / Nc, n = idx % Nc;
    Wdst[(size_t)n * K + k] = f2bf(Wsrc[idx]);
}

// ---- fused GEMM: C = A @ Bt^T (+bias + epilogue) ----
// EPI 0: edge message: relu(acc + bias + h[src]) atomically scattered to agg[dst]
// EPI 1: t = bf16(gelu(acc + bias))
// EPI 2: out = xres + gelu(acc + bias)
template <int EPI, bool ABF16>
__global__ __launch_bounds__(256) void gemm_fused(
    const void* __restrict__ Ap, const unsigned short* __restrict__ Bt,
    const float* __restrict__ bias, int M, int K,
    const int* __restrict__ eidx, int E,
    const unsigned short* __restrict__ hb, float* __restrict__ agg,
    unsigned short* __restrict__ outb,
    const float* __restrict__ xres, float* __restrict__ outf, int ldo) {
    __shared__ unsigned short As[128][40];
    __shared__ unsigned short Bs[128][40];
    const int t = threadIdx.x;
    const int m0 = blockIdx.x * 128;
    const int n0 = blockIdx.y * 128;
    const int sr = t >> 1;          // staging row 0..127
    const int sh = (t & 1) << 4;    // staging col half: 0 or 16
    const int lane = t & 63;
    const int wid = t >> 6;
    const int wr = (wid >> 1) << 6; // wave row offset (0/64)
    const int wc = (wid & 1) << 6;  // wave col offset (0/64)
    const int fr = lane & 15;
    const int kg = lane >> 4;

    f32x4 acc[4][4];
#pragma unroll
    for (int i = 0; i < 4; i++)
#pragma unroll
        for (int j = 0; j < 4; j++) acc[i][j] = (f32x4){0.f, 0.f, 0.f, 0.f};

    const bool arok = (m0 + sr) < M;
    const size_t arowoff = (size_t)(m0 + sr) * K;
    const unsigned short* Brow = Bt + (size_t)(n0 + sr) * K + sh;

    for (int k0 = 0; k0 < K; k0 += 32) {
        if (ABF16) {
            uint4 v0 = {0, 0, 0, 0}, v1 = {0, 0, 0, 0};
            if (arok) {
                const uint4* p = (const uint4*)((const unsigned short*)Ap + arowoff + k0 + sh);
                v0 = p[0]; v1 = p[1];
            }
            *(uint4*)&As[sr][sh] = v0;
            *(uint4*)&As[sr][sh + 8] = v1;
        } else {
            uint4 w0 = {0, 0, 0, 0}, w1 = {0, 0, 0, 0};
            if (arok) {
                const float4* p = (const float4*)((const float*)Ap + arowoff + k0 + sh);
                float4 f0 = p[0], f1 = p[1], f2 = p[2], f3 = p[3];
                w0.x = pk2(f0.x, f0.y); w0.y = pk2(f0.z, f0.w);
                w0.z = pk2(f1.x, f1.y); w0.w = pk2(f1.z, f1.w);
                w1.x = pk2(f2.x, f2.y); w1.y = pk2(f2.z, f2.w);
                w1.z = pk2(f3.x, f3.y); w1.w = pk2(f3.z, f3.w);
            }
            *(uint4*)&As[sr][sh] = w0;
            *(uint4*)&As[sr][sh + 8] = w1;
        }
        {
            const uint4* p = (const uint4*)(Brow + k0);
            *(uint4*)&Bs[sr][sh] = p[0];
            *(uint4*)&Bs[sr][sh + 8] = p[1];
        }
        __syncthreads();
        bf16x8 a[4], b[4];
#pragma unroll
        for (int i = 0; i < 4; i++) a[i] = *(const bf16x8*)&As[wr + i * 16 + fr][kg * 8];
#pragma unroll
        for (int j = 0; j < 4; j++) b[j] = *(const bf16x8*)&Bs[wc + j * 16 + fr][kg * 8];
#pragma unroll
        for (int i = 0; i < 4; i++)
#pragma unroll
            for (int j = 0; j < 4; j++)
                acc[i][j] = __builtin_amdgcn_mfma_f32_16x16x32_bf16(a[i], b[j], acc[i][j], 0, 0, 0);
        __syncthreads();
    }

    const int kg4 = kg * 4;
#pragma unroll
    for (int i = 0; i < 4; i++) {
        const int rb = m0 + wr + i * 16 + kg4;
#pragma unroll
        for (int j = 0; j < 4; j++) {
            const int c = n0 + wc + j * 16 + fr;
#pragma unroll
            for (int r = 0; r < 4; r++) {
                const int row = rb + r;
                if (row < M) {
                    float v = acc[i][j][r] + bias[c];
                    if (EPI == 0) {
                        int s = eidx[row];
                        int dd = eidx[E + row];
                        v += bf2f(hb[(size_t)s * Df + c]);
                        v = fmaxf(v, 0.f);
                        unsafeAtomicAdd(&agg[(size_t)dd * Df + c], v);
                    } else if (EPI == 1) {
                        outb[(size_t)row * ldo + c] = f2bf(gelu_(v));
                    } else {
                        size_t o = (size_t)row * ldo + c;
                        outf[o] = xres[o] + gelu_(v);
                    }
                }
            }
        }
    }
}

extern "C" void kernel_launch(void* const* d_in, const int* in_sizes, int n_in,
                              void* d_out, int out_size, void* d_ws, size_t ws_size,
                              hipStream_t stream) {
    const float* x = (const float*)d_in[0];
    const float* ea = (const float*)d_in[1];
    const float* gamma = (const float*)d_in[2];
    const float* beta = (const float*)d_in[3];
    const float* epsp = (const float*)d_in[4];
    const float* W_edge = (const float*)d_in[5];
    const float* b_edge = (const float*)d_in[6];
    const float* W1 = (const float*)d_in[7];
    const float* b1 = (const float*)d_in[8];
    const float* W2 = (const float*)d_in[9];
    const float* b2 = (const float*)d_in[10];
    const int* eidx = (const int*)d_in[11];
    float* out = (float*)d_out;
    const int N = in_sizes[0] / Df;
    const int E = in_sizes[1] / Df;

    char* w = (char*)d_ws;
    float* stats = (float*)w;          // 768 f32: sum, sumsq
    float* coef = stats + 2 * Df;      // 768 f32: a, b
    size_t off = 8192;
    unsigned short* hb = (unsigned short*)(w + off); off += (size_t)N * Df * 2;
    unsigned short* zb = (unsigned short*)(w + off); off += (size_t)N * Df * 2;
    float* agg = (float*)(w + off);                    // [N][384] f32
    unsigned short* tb = (unsigned short*)agg;         // reused: [N][768] bf16
    off += (size_t)N * Df * 4;
    unsigned short* WeT = (unsigned short*)(w + off); off += (size_t)Df * Df * 2;
    unsigned short* W1T = (unsigned short*)(w + off); off += (size_t)Df * Hf * 2;
    unsigned short* W2T = (unsigned short*)(w + off); off += (size_t)Hf * Df * 2;
    (void)ws_size; (void)n_in; (void)out_size;

    hipMemsetAsync(stats, 0, 2 * Df * sizeof(float), stream);
    hipMemsetAsync(agg, 0, (size_t)N * Df * sizeof(float), stream);

    bn_stats<<<1024, 192, 0, stream>>>(x, stats, N);
    bn_finalize<<<1, Df, 0, stream>>>(stats, gamma, beta, coef, N);

    int tot8 = N * Df / 8;
    h_kernel<<<(tot8 + 255) / 256, 256, 0, stream>>>(x, coef, hb, tot8);

    wtrans<<<(Df * Df + 255) / 256, 256, 0, stream>>>(W_edge, WeT, Df, Df);
    wtrans<<<(Df * Hf + 255) / 256, 256, 0, stream>>>(W1, W1T, Df, Hf);
    wtrans<<<(Hf * Df + 255) / 256, 256, 0, stream>>>(W2, W2T, Hf, Df);

    dim3 ge((E + 127) / 128, Df / 128);
    gemm_fused<0, false><<<ge, 256, 0, stream>>>(ea, WeT, b_edge, E, Df,
                                                 eidx, E, hb, agg, nullptr, nullptr, nullptr, Df);

    z_kernel<<<(tot8 + 255) / 256, 256, 0, stream>>>(hb, agg, epsp, zb, tot8);

    dim3 g1((N + 127) / 128, Hf / 128);
    gemm_fused<1, true><<<g1, 256, 0, stream>>>(zb, W1T, b1, N, Df,
                                                nullptr, 0, nullptr, nullptr, tb, nullptr, nullptr, Hf);

    dim3 g2((N + 127) / 128, Df / 128);
    gemm_fused<2, true><<<g2, 256, 0, stream>>>(tb, W2T, b2, N, Hf,
                                                nullptr, 0, nullptr, nullptr, nullptr, x, out, Df);
}

// Round 2
// 1188.461 us; speedup vs baseline: 1.2685x; 1.2685x over previous
//
#include <hip/hip_runtime.h>
#include <hip/hip_bf16.h>

#define Df 384
#define Hf 768
#define SCAN_CH 4096

typedef __bf16 bf16x8 __attribute__((ext_vector_type(8)));
typedef float f32x4 __attribute__((ext_vector_type(4)));

struct __attribute__((aligned(4))) U12 { unsigned int x, y, z; };

__device__ inline unsigned short f2bf(float f) {
    __hip_bfloat16 h = __float2bfloat16(f);
    return __builtin_bit_cast(unsigned short, h);
}
__device__ inline float bf2f(unsigned short u) {
    unsigned int v = ((unsigned int)u) << 16;
    return __builtin_bit_cast(float, v);
}
__device__ inline float lobf(unsigned int v) { return bf2f((unsigned short)(v & 0xffff)); }
__device__ inline float hibf(unsigned int v) { return bf2f((unsigned short)(v >> 16)); }
__device__ inline unsigned int pk2(float a, float b) {
    return (unsigned int)f2bf(a) | ((unsigned int)f2bf(b) << 16);
}
__device__ inline float gelu_(float v) {
    return 0.5f * v * (1.0f + erff(v * 0.70710678118654752f));
}

// ---- BN column statistics: sum + sumsq per feature ----
__global__ void bn_stats(const float* __restrict__ x, float* __restrict__ stats, int N) {
    int t = threadIdx.x;                 // 192 threads
    int c4 = (t % 96) * 4;
    int rs = t / 96;
    float s0 = 0, s1 = 0, s2 = 0, s3 = 0, q0 = 0, q1 = 0, q2 = 0, q3 = 0;
    for (int r = blockIdx.x * 2 + rs; r < N; r += gridDim.x * 2) {
        float4 v = *(const float4*)(x + (size_t)r * Df + c4);
        s0 += v.x; s1 += v.y; s2 += v.z; s3 += v.w;
        q0 += v.x * v.x; q1 += v.y * v.y; q2 += v.z * v.z; q3 += v.w * v.w;
    }
    unsafeAtomicAdd(&stats[c4 + 0], s0);
    unsafeAtomicAdd(&stats[c4 + 1], s1);
    unsafeAtomicAdd(&stats[c4 + 2], s2);
    unsafeAtomicAdd(&stats[c4 + 3], s3);
    unsafeAtomicAdd(&stats[Df + c4 + 0], q0);
    unsafeAtomicAdd(&stats[Df + c4 + 1], q1);
    unsafeAtomicAdd(&stats[Df + c4 + 2], q2);
    unsafeAtomicAdd(&stats[Df + c4 + 3], q3);
}

__global__ void bn_finalize(const float* __restrict__ stats,
                            const float* __restrict__ gamma,
                            const float* __restrict__ beta,
                            float* __restrict__ coef, int N) {
    int c = threadIdx.x; // 384
    float invN = 1.0f / (float)N;
    float mu = stats[c] * invN;
    float var = stats[Df + c] * invN - mu * mu;
    float rs = rsqrtf(var + 1e-5f);
    float a = gamma[c] * rs;
    coef[c] = a;
    coef[Df + c] = beta[c] - mu * a;
}

// ---- h = x*a + b  ->  bf16 ----
__global__ void h_kernel(const float* __restrict__ x, const float* __restrict__ coef,
                         unsigned short* __restrict__ hb, int tot8) {
    int i = blockIdx.x * 256 + threadIdx.x;
    if (i >= tot8) return;
    size_t base = (size_t)i * 8;
    int c = (int)(base % Df);
    float4 x0 = *(const float4*)(x + base);
    float4 x1 = *(const float4*)(x + base + 4);
    const float* a = coef + c;
    const float* b = coef + Df + c;
    uint4 o;
    o.x = pk2(x0.x * a[0] + b[0], x0.y * a[1] + b[1]);
    o.y = pk2(x0.z * a[2] + b[2], x0.w * a[3] + b[3]);
    o.z = pk2(x1.x * a[4] + b[4], x1.y * a[5] + b[5]);
    o.w = pk2(x1.z * a[6] + b[6], x1.w * a[7] + b[7]);
    *(uint4*)(hb + base) = o;
}

// ---- weight transpose + cast: W[K][Nc] f32 -> Wt[Nc][K] bf16 ----
__global__ void wtrans(const float* __restrict__ Wsrc, unsigned short* __restrict__ Wdst,
                       int K, int Nc) {
    int idx = blockIdx.x * 256 + threadIdx.x;
    if (idx >= K * Nc) return;
    int k = idx / Nc, n = idx % Nc;
    Wdst[(size_t)n * K + k] = f2bf(Wsrc[idx]);
}

// ---- CSR build ----
__global__ void degree_k(const int* __restrict__ dst, int* __restrict__ deg, int E) {
    int e = blockIdx.x * 256 + threadIdx.x;
    if (e < E) atomicAdd(&deg[dst[e]], 1);
}

__global__ void scan1(const int* __restrict__ deg, int* __restrict__ off,
                      int* __restrict__ sums, int N) {
    __shared__ int ts[256];
    int t = threadIdx.x;
    int base = blockIdx.x * SCAN_CH + t * 16;
    int v[16];
    int s = 0;
    for (int j = 0; j < 16; j++) {
        int idx = base + j;
        int d = (idx < N) ? deg[idx] : 0;
        v[j] = s;
        s += d;
    }
    ts[t] = s;
    __syncthreads();
    for (int o = 1; o < 256; o <<= 1) {
        int add = (t >= o) ? ts[t - o] : 0;
        __syncthreads();
        ts[t] += add;
        __syncthreads();
    }
    int pre = t ? ts[t - 1] : 0;
    for (int j = 0; j < 16; j++) {
        int idx = base + j;
        if (idx < N) off[idx] = pre + v[j];
    }
    if (t == 255) sums[blockIdx.x] = ts[255];
}

__global__ void scan2(int* __restrict__ sums, int nb) {
    int acc = 0;
    for (int b = 0; b < nb; b++) { int v = sums[b]; sums[b] = acc; acc += v; }
    sums[nb] = acc;
}

__global__ void scan3(int* __restrict__ off, const int* __restrict__ sums, int N, int nb) {
    int idx = blockIdx.x * 256 + threadIdx.x;
    if (idx < N) off[idx] += sums[idx / SCAN_CH];
    else if (idx == N) off[N] = sums[nb];
}

__global__ void fill_k(const int* __restrict__ dst, int* __restrict__ cursor,
                       int* __restrict__ eid, int E) {
    int e = blockIdx.x * 256 + threadIdx.x;
    if (e >= E) return;
    int pos = atomicAdd(&cursor[dst[e]], 1);
    eid[pos] = e;
}

// ---- gather-reduce: z[i] = (1+eps)*h[i] + sum_{e in adj(i)} relu(msgl[e] + h[src[e]]) ----
__global__ __launch_bounds__(256) void aggregate(
    const unsigned short* __restrict__ msgl, const unsigned short* __restrict__ hb,
    const int* __restrict__ off, const int* __restrict__ eid,
    const int* __restrict__ edge_src, const float* __restrict__ epsp,
    unsigned short* __restrict__ zb, int N) {
    int lane = threadIdx.x & 63;
    int wid = threadIdx.x >> 6;
    int nwaves = gridDim.x * 4;
    float s1p = 1.0f + epsp[0];
    int loff = lane * 6;
    for (int i = blockIdx.x * 4 + wid; i < N; i += nwaves) {
        int o0 = off[i], o1 = off[i + 1];
        float a0 = 0, a1 = 0, a2 = 0, a3 = 0, a4 = 0, a5 = 0;
        for (int p = o0; p < o1; ++p) {
            int e = eid[p];
            int s = edge_src[e];
            U12 mv = *(const U12*)(msgl + (size_t)e * Df + loff);
            U12 hv = *(const U12*)(hb + (size_t)s * Df + loff);
            a0 += fmaxf(lobf(mv.x) + lobf(hv.x), 0.f);
            a1 += fmaxf(hibf(mv.x) + hibf(hv.x), 0.f);
            a2 += fmaxf(lobf(mv.y) + lobf(hv.y), 0.f);
            a3 += fmaxf(hibf(mv.y) + hibf(hv.y), 0.f);
            a4 += fmaxf(lobf(mv.z) + lobf(hv.z), 0.f);
            a5 += fmaxf(hibf(mv.z) + hibf(hv.z), 0.f);
        }
        U12 hv = *(const U12*)(hb + (size_t)i * Df + loff);
        U12 o;
        o.x = pk2(s1p * lobf(hv.x) + a0, s1p * hibf(hv.x) + a1);
        o.y = pk2(s1p * lobf(hv.y) + a2, s1p * hibf(hv.y) + a3);
        o.z = pk2(s1p * lobf(hv.z) + a4, s1p * hibf(hv.z) + a5);
        *(U12*)(zb + (size_t)i * Df + loff) = o;
    }
}

// ---- fused GEMM: C = A @ Bt^T (+bias + epilogue) ----
// EPI 1: out = bf16(gelu(acc + bias))
// EPI 2: out = xres + gelu(acc + bias)   (f32)
// EPI 3: out = bf16(acc + bias)
template <int EPI, bool ABF16>
__global__ __launch_bounds__(256) void gemm_fused(
    const void* __restrict__ Ap, const unsigned short* __restrict__ Bt,
    const float* __restrict__ bias, int M, int K,
    unsigned short* __restrict__ outb,
    const float* __restrict__ xres, float* __restrict__ outf, int ldo) {
    __shared__ unsigned short As[128][40];
    __shared__ unsigned short Bs[128][40];
    const int t = threadIdx.x;
    const int m0 = blockIdx.x * 128;
    const int n0 = blockIdx.y * 128;
    const int sr = t >> 1;
    const int sh = (t & 1) << 4;
    const int lane = t & 63;
    const int wid = t >> 6;
    const int wr = (wid >> 1) << 6;
    const int wc = (wid & 1) << 6;
    const int fr = lane & 15;
    const int kg = lane >> 4;

    f32x4 acc[4][4];
#pragma unroll
    for (int i = 0; i < 4; i++)
#pragma unroll
        for (int j = 0; j < 4; j++) acc[i][j] = (f32x4){0.f, 0.f, 0.f, 0.f};

    const bool arok = (m0 + sr) < M;
    const size_t arowoff = (size_t)(m0 + sr) * K;
    const unsigned short* Brow = Bt + (size_t)(n0 + sr) * K + sh;

    for (int k0 = 0; k0 < K; k0 += 32) {
        if (ABF16) {
            uint4 v0 = {0, 0, 0, 0}, v1 = {0, 0, 0, 0};
            if (arok) {
                const uint4* p = (const uint4*)((const unsigned short*)Ap + arowoff + k0 + sh);
                v0 = p[0]; v1 = p[1];
            }
            *(uint4*)&As[sr][sh] = v0;
            *(uint4*)&As[sr][sh + 8] = v1;
        } else {
            uint4 w0 = {0, 0, 0, 0}, w1 = {0, 0, 0, 0};
            if (arok) {
                const float4* p = (const float4*)((const float*)Ap + arowoff + k0 + sh);
                float4 f0 = p[0], f1 = p[1], f2 = p[2], f3 = p[3];
                w0.x = pk2(f0.x, f0.y); w0.y = pk2(f0.z, f0.w);
                w0.z = pk2(f1.x, f1.y); w0.w = pk2(f1.z, f1.w);
                w1.x = pk2(f2.x, f2.y); w1.y = pk2(f2.z, f2.w);
                w1.z = pk2(f3.x, f3.y); w1.w = pk2(f3.z, f3.w);
            }
            *(uint4*)&As[sr][sh] = w0;
            *(uint4*)&As[sr][sh + 8] = w1;
        }
        {
            const uint4* p = (const uint4*)(Brow + k0);
            *(uint4*)&Bs[sr][sh] = p[0];
            *(uint4*)&Bs[sr][sh + 8] = p[1];
        }
        __syncthreads();
        bf16x8 a[4], b[4];
#pragma unroll
        for (int i = 0; i < 4; i++) a[i] = *(const bf16x8*)&As[wr + i * 16 + fr][kg * 8];
#pragma unroll
        for (int j = 0; j < 4; j++) b[j] = *(const bf16x8*)&Bs[wc + j * 16 + fr][kg * 8];
#pragma unroll
        for (int i = 0; i < 4; i++)
#pragma unroll
            for (int j = 0; j < 4; j++)
                acc[i][j] = __builtin_amdgcn_mfma_f32_16x16x32_bf16(a[i], b[j], acc[i][j], 0, 0, 0);
        __syncthreads();
    }

    const int kg4 = kg * 4;
#pragma unroll
    for (int i = 0; i < 4; i++) {
        const int rb = m0 + wr + i * 16 + kg4;
#pragma unroll
        for (int j = 0; j < 4; j++) {
            const int c = n0 + wc + j * 16 + fr;
#pragma unroll
            for (int r = 0; r < 4; r++) {
                const int row = rb + r;
                if (row < M) {
                    float v = acc[i][j][r] + bias[c];
                    if (EPI == 1) {
                        outb[(size_t)row * ldo + c] = f2bf(gelu_(v));
                    } else if (EPI == 2) {
                        size_t o = (size_t)row * ldo + c;
                        outf[o] = xres[o] + gelu_(v);
                    } else {
                        outb[(size_t)row * ldo + c] = f2bf(v);
                    }
                }
            }
        }
    }
}

extern "C" void kernel_launch(void* const* d_in, const int* in_sizes, int n_in,
                              void* d_out, int out_size, void* d_ws, size_t ws_size,
                              hipStream_t stream) {
    const float* x = (const float*)d_in[0];
    const float* ea = (const float*)d_in[1];
    const float* gamma = (const float*)d_in[2];
    const float* beta = (const float*)d_in[3];
    const float* epsp = (const float*)d_in[4];
    const float* W_edge = (const float*)d_in[5];
    const float* b_edge = (const float*)d_in[6];
    const float* W1 = (const float*)d_in[7];
    const float* b1 = (const float*)d_in[8];
    const float* W2 = (const float*)d_in[9];
    const float* b2 = (const float*)d_in[10];
    const int* eidx = (const int*)d_in[11];
    float* out = (float*)d_out;
    const int N = in_sizes[0] / Df;
    const int E = in_sizes[1] / Df;
    const int* esrc = eidx;
    const int* edst = eidx + E;

    char* w = (char*)d_ws;
    size_t off_ = 0;
    auto alloc = [&](size_t bytes) { char* p = w + off_; off_ += (bytes + 255) & ~(size_t)255; return p; };
    float* stats = (float*)alloc(2 * Df * sizeof(float));
    float* coef = (float*)alloc(2 * Df * sizeof(float));
    unsigned short* hb = (unsigned short*)alloc((size_t)N * Df * 2);
    unsigned short* zb = (unsigned short*)alloc((size_t)N * Df * 2);
    unsigned short* tb = (unsigned short*)alloc((size_t)N * Hf * 2);
    unsigned short* WeT = (unsigned short*)alloc((size_t)Df * Df * 2);
    unsigned short* W1T = (unsigned short*)alloc((size_t)Df * Hf * 2);
    unsigned short* W2T = (unsigned short*)alloc((size_t)Hf * Df * 2);
    int* deg = (int*)alloc((size_t)(N + 1) * 4);      // reused as fill cursor
    int* offs = (int*)alloc((size_t)(N + 1) * 4);
    int* eid = (int*)alloc((size_t)E * 4);
    int* sums = (int*)alloc(64 * 4);
    // msgl: spare ws if it fits, else borrow d_out (dead until final GEMM writes it)
    size_t msgl_bytes = (size_t)E * Df * 2;
    unsigned short* msgl;
    if (off_ + msgl_bytes <= ws_size) msgl = (unsigned short*)alloc(msgl_bytes);
    else msgl = (unsigned short*)d_out;
    (void)n_in; (void)out_size;

    hipMemsetAsync(stats, 0, 2 * Df * sizeof(float), stream);
    hipMemsetAsync(deg, 0, (size_t)N * 4, stream);

    // BN + h
    bn_stats<<<1024, 192, 0, stream>>>(x, stats, N);
    bn_finalize<<<1, Df, 0, stream>>>(stats, gamma, beta, coef, N);
    int tot8 = N * Df / 8;
    h_kernel<<<(tot8 + 255) / 256, 256, 0, stream>>>(x, coef, hb, tot8);

    // weights
    wtrans<<<(Df * Df + 255) / 256, 256, 0, stream>>>(W_edge, WeT, Df, Df);
    wtrans<<<(Df * Hf + 255) / 256, 256, 0, stream>>>(W1, W1T, Df, Hf);
    wtrans<<<(Hf * Df + 255) / 256, 256, 0, stream>>>(W2, W2T, Hf, Df);

    // CSR by dst
    int nb = (N + SCAN_CH - 1) / SCAN_CH;
    degree_k<<<(E + 255) / 256, 256, 0, stream>>>(edst, deg, E);
    scan1<<<nb, 256, 0, stream>>>(deg, offs, sums, N);
    scan2<<<1, 1, 0, stream>>>(sums, nb);
    scan3<<<(N + 256) / 256, 256, 0, stream>>>(offs, sums, N, nb);
    hipMemcpyAsync(deg, offs, (size_t)N * 4, hipMemcpyDeviceToDevice, stream);
    fill_k<<<(E + 255) / 256, 256, 0, stream>>>(edst, deg, eid, E);

    // edge linear: msgl = ea @ We^T + b_edge  (bf16)
    dim3 ge((E + 127) / 128, Df / 128);
    gemm_fused<3, false><<<ge, 256, 0, stream>>>(ea, WeT, b_edge, E, Df,
                                                 msgl, nullptr, nullptr, Df);

    // gather-reduce -> z (bf16)
    aggregate<<<2048, 256, 0, stream>>>(msgl, hb, offs, eid, esrc, epsp, zb, N);

    // MLP
    dim3 g1((N + 127) / 128, Hf / 128);
    gemm_fused<1, true><<<g1, 256, 0, stream>>>(zb, W1T, b1, N, Df,
                                                tb, nullptr, nullptr, Hf);
    dim3 g2((N + 127) / 128, Df / 128);
    gemm_fused<2, true><<<g2, 256, 0, stream>>>(tb, W2T, b2, N, Hf,
                                                nullptr, x, out, Df);
}

// Round 3
// 1114.123 us; speedup vs baseline: 1.3532x; 1.0667x over previous
//
#include <hip/hip_runtime.h>
#include <hip/hip_bf16.h>

#define Df 384
#define Hf 768
#define SCAN_CH 4096

typedef __bf16 bf16x8 __attribute__((ext_vector_type(8)));
typedef float f32x4 __attribute__((ext_vector_type(4)));

struct __attribute__((aligned(4))) U12 { unsigned int x, y, z; };

__device__ inline unsigned short f2bf(float f) {
    __hip_bfloat16 h = __float2bfloat16(f);
    return __builtin_bit_cast(unsigned short, h);
}
__device__ inline float bf2f(unsigned short u) {
    unsigned int v = ((unsigned int)u) << 16;
    return __builtin_bit_cast(float, v);
}
__device__ inline float lobf(unsigned int v) { return bf2f((unsigned short)(v & 0xffff)); }
__device__ inline float hibf(unsigned int v) { return bf2f((unsigned short)(v >> 16)); }
__device__ inline unsigned int pk2(float a, float b) {
    return (unsigned int)f2bf(a) | ((unsigned int)f2bf(b) << 16);
}
__device__ inline float gelu_(float v) {
    return 0.5f * v * (1.0f + erff(v * 0.70710678118654752f));
}
// direct global->LDS, 16B per lane; LDS dest = wave-uniform base + lane*16
__device__ inline void gload16(const void* g, void* l) {
    __builtin_amdgcn_global_load_lds(
        (const __attribute__((address_space(1))) unsigned int*)g,
        (__attribute__((address_space(3))) unsigned int*)l, 16, 0, 0);
}

// ---- BN column statistics: sum + sumsq per feature ----
__global__ void bn_stats(const float* __restrict__ x, float* __restrict__ stats, int N) {
    int t = threadIdx.x;                 // 192 threads
    int c4 = (t % 96) * 4;
    int rs = t / 96;
    float s0 = 0, s1 = 0, s2 = 0, s3 = 0, q0 = 0, q1 = 0, q2 = 0, q3 = 0;
    for (int r = blockIdx.x * 2 + rs; r < N; r += gridDim.x * 2) {
        float4 v = *(const float4*)(x + (size_t)r * Df + c4);
        s0 += v.x; s1 += v.y; s2 += v.z; s3 += v.w;
        q0 += v.x * v.x; q1 += v.y * v.y; q2 += v.z * v.z; q3 += v.w * v.w;
    }
    unsafeAtomicAdd(&stats[c4 + 0], s0);
    unsafeAtomicAdd(&stats[c4 + 1], s1);
    unsafeAtomicAdd(&stats[c4 + 2], s2);
    unsafeAtomicAdd(&stats[c4 + 3], s3);
    unsafeAtomicAdd(&stats[Df + c4 + 0], q0);
    unsafeAtomicAdd(&stats[Df + c4 + 1], q1);
    unsafeAtomicAdd(&stats[Df + c4 + 2], q2);
    unsafeAtomicAdd(&stats[Df + c4 + 3], q3);
}

__global__ void bn_finalize(const float* __restrict__ stats,
                            const float* __restrict__ gamma,
                            const float* __restrict__ beta,
                            float* __restrict__ coef, int N) {
    int c = threadIdx.x; // 384
    float invN = 1.0f / (float)N;
    float mu = stats[c] * invN;
    float var = stats[Df + c] * invN - mu * mu;
    float rs = rsqrtf(var + 1e-5f);
    float a = gamma[c] * rs;
    coef[c] = a;
    coef[Df + c] = beta[c] - mu * a;
}

// ---- h = x*a + b  ->  bf16 ----
__global__ void h_kernel(const float* __restrict__ x, const float* __restrict__ coef,
                         unsigned short* __restrict__ hb, int tot8) {
    int i = blockIdx.x * 256 + threadIdx.x;
    if (i >= tot8) return;
    size_t base = (size_t)i * 8;
    int c = (int)(base % Df);
    float4 x0 = *(const float4*)(x + base);
    float4 x1 = *(const float4*)(x + base + 4);
    const float* a = coef + c;
    const float* b = coef + Df + c;
    uint4 o;
    o.x = pk2(x0.x * a[0] + b[0], x0.y * a[1] + b[1]);
    o.y = pk2(x0.z * a[2] + b[2], x0.w * a[3] + b[3]);
    o.z = pk2(x1.x * a[4] + b[4], x1.y * a[5] + b[5]);
    o.w = pk2(x1.z * a[6] + b[6], x1.w * a[7] + b[7]);
    *(uint4*)(hb + base) = o;
}

// ---- weight transpose + cast: W[K][Nc] f32 -> Wt[Nc][K] bf16 ----
__global__ void wtrans(const float* __restrict__ Wsrc, unsigned short* __restrict__ Wdst,
                       int K, int Nc) {
    int idx = blockIdx.x * 256 + threadIdx.x;
    if (idx >= K * Nc) return;
    int k = idx / Nc, n = idx % Nc;
    Wdst[(size_t)n * K + k] = f2bf(Wsrc[idx]);
}

// ---- CSR build ----
__global__ void degree_k(const int* __restrict__ dst, int* __restrict__ deg, int E) {
    int e = blockIdx.x * 256 + threadIdx.x;
    if (e < E) atomicAdd(&deg[dst[e]], 1);
}

__global__ void scan1(const int* __restrict__ deg, int* __restrict__ off,
                      int* __restrict__ sums, int N) {
    __shared__ int ts[256];
    int t = threadIdx.x;
    int base = blockIdx.x * SCAN_CH + t * 16;
    int v[16];
    int s = 0;
    for (int j = 0; j < 16; j++) {
        int idx = base + j;
        int d = (idx < N) ? deg[idx] : 0;
        v[j] = s;
        s += d;
    }
    ts[t] = s;
    __syncthreads();
    for (int o = 1; o < 256; o <<= 1) {
        int add = (t >= o) ? ts[t - o] : 0;
        __syncthreads();
        ts[t] += add;
        __syncthreads();
    }
    int pre = t ? ts[t - 1] : 0;
    for (int j = 0; j < 16; j++) {
        int idx = base + j;
        if (idx < N) off[idx] = pre + v[j];
    }
    if (t == 255) sums[blockIdx.x] = ts[255];
}

__global__ void scan2(int* __restrict__ sums, int nb) {
    int acc = 0;
    for (int b = 0; b < nb; b++) { int v = sums[b]; sums[b] = acc; acc += v; }
    sums[nb] = acc;
}

__global__ void scan3(int* __restrict__ off, const int* __restrict__ sums, int N, int nb) {
    int idx = blockIdx.x * 256 + threadIdx.x;
    if (idx < N) off[idx] += sums[idx / SCAN_CH];
    else if (idx == N) off[N] = sums[nb];
}

// fill: pose[e] = CSR slot of edge e; srcp[slot] = src node of that edge
__global__ void fill_k(const int* __restrict__ dst, const int* __restrict__ src,
                       int* __restrict__ cursor, int* __restrict__ srcp,
                       int* __restrict__ pose, int E) {
    int e = blockIdx.x * 256 + threadIdx.x;
    if (e >= E) return;
    int pos = atomicAdd(&cursor[dst[e]], 1);
    srcp[pos] = src[e];
    pose[e] = pos;
}

// ---- gather-reduce: z[i] = (1+eps)*h[i] + sum_{p in [off[i],off[i+1])} relu(msgl[p] + h[srcp[p]]) ----
__global__ __launch_bounds__(256) void aggregate(
    const unsigned short* __restrict__ msgl, const unsigned short* __restrict__ hb,
    const int* __restrict__ off, const int* __restrict__ srcp,
    const float* __restrict__ epsp,
    unsigned short* __restrict__ zb, int N) {
    int lane = threadIdx.x & 63;
    int wid = threadIdx.x >> 6;
    int nwaves = gridDim.x * 4;
    float s1p = 1.0f + epsp[0];
    int loff = lane * 6;
    for (int i = blockIdx.x * 4 + wid; i < N; i += nwaves) {
        int o0 = off[i], o1 = off[i + 1];
        float a0 = 0, a1 = 0, a2 = 0, a3 = 0, a4 = 0, a5 = 0;
        for (int p = o0; p < o1; ++p) {
            int s = srcp[p];
            U12 mv = *(const U12*)(msgl + (size_t)p * Df + loff);
            U12 hv = *(const U12*)(hb + (size_t)s * Df + loff);
            a0 += fmaxf(lobf(mv.x) + lobf(hv.x), 0.f);
            a1 += fmaxf(hibf(mv.x) + hibf(hv.x), 0.f);
            a2 += fmaxf(lobf(mv.y) + lobf(hv.y), 0.f);
            a3 += fmaxf(hibf(mv.y) + hibf(hv.y), 0.f);
            a4 += fmaxf(lobf(mv.z) + lobf(hv.z), 0.f);
            a5 += fmaxf(hibf(mv.z) + hibf(hv.z), 0.f);
        }
        U12 hv = *(const U12*)(hb + (size_t)i * Df + loff);
        U12 o;
        o.x = pk2(s1p * lobf(hv.x) + a0, s1p * hibf(hv.x) + a1);
        o.y = pk2(s1p * lobf(hv.y) + a2, s1p * hibf(hv.y) + a3);
        o.z = pk2(s1p * lobf(hv.z) + a4, s1p * hibf(hv.z) + a5);
        *(U12*)(zb + (size_t)i * Df + loff) = o;
    }
}

// ---- fused GEMM: C = A @ Bt^T (+bias + epilogue) ----
// Grid: blockIdx.x = column block (fastest -> A-panel L2/L3 reuse), blockIdx.y = row block.
// EPI 1: out = bf16(gelu(acc + bias))
// EPI 2: out = xres + gelu(acc + bias)   (f32)
// EPI 3: out row permuted via pose: outb[pose[row]] = bf16(acc + bias)
template <int EPI, bool ABF16>
__global__ __launch_bounds__(256) void gemm_fused(
    const void* __restrict__ Ap, const unsigned short* __restrict__ Bt,
    const float* __restrict__ bias, int M, int K,
    const int* __restrict__ pose,
    unsigned short* __restrict__ outb,
    const float* __restrict__ xres, float* __restrict__ outf, int ldo) {
    __shared__ __align__(16) unsigned short As[128 * 32];
    __shared__ __align__(16) unsigned short Bs[128 * 32];
    const int t = threadIdx.x;
    const int n0 = blockIdx.x * 128;
    const int m0 = blockIdx.y * 128;
    const int lane = t & 63;
    const int wid = t >> 6;
    const int wr = (wid >> 1) << 6;
    const int wc = (wid & 1) << 6;
    const int fr = lane & 15;
    const int kg = lane >> 4;
    // gload lane coords: 1KB chunk = 16 rows x 64B; lane covers row (lane>>2), 16B seg (lane&3)
    const int crow = lane >> 2;
    const int cseg = lane & 3;
    // f32-convert path coords
    const int sr = t >> 1;
    const int sh = (t & 1) << 4;

    f32x4 acc[4][4];
#pragma unroll
    for (int i = 0; i < 4; i++)
#pragma unroll
        for (int j = 0; j < 4; j++) acc[i][j] = (f32x4){0.f, 0.f, 0.f, 0.f};

    const bool arok = (m0 + sr) < M;
    const size_t arowoff = (size_t)(m0 + sr) * K;

    for (int k0 = 0; k0 < K; k0 += 32) {
        if (ABF16) {
            const unsigned short* Ab = (const unsigned short*)Ap;
#pragma unroll
            for (int c = 0; c < 2; c++) {
                const int row = wid * 32 + c * 16 + crow;
                if (m0 + row < M)
                    gload16(Ab + (size_t)(m0 + row) * K + k0 + cseg * 8,
                            &As[(wid * 32 + c * 16) * 32]);
            }
        } else {
            uint4 w0 = {0, 0, 0, 0}, w1 = {0, 0, 0, 0};
            if (arok) {
                const float4* p = (const float4*)((const float*)Ap + arowoff + k0 + sh);
                float4 f0 = p[0], f1 = p[1], f2 = p[2], f3 = p[3];
                w0.x = pk2(f0.x, f0.y); w0.y = pk2(f0.z, f0.w);
                w0.z = pk2(f1.x, f1.y); w0.w = pk2(f1.z, f1.w);
                w1.x = pk2(f2.x, f2.y); w1.y = pk2(f2.z, f2.w);
                w1.z = pk2(f3.x, f3.y); w1.w = pk2(f3.z, f3.w);
            }
            *(uint4*)&As[sr * 32 + sh] = w0;
            *(uint4*)&As[sr * 32 + sh + 8] = w1;
        }
#pragma unroll
        for (int c = 0; c < 2; c++) {
            const int row = wid * 32 + c * 16 + crow;
            gload16(Bt + (size_t)(n0 + row) * K + k0 + cseg * 8,
                    &Bs[(wid * 32 + c * 16) * 32]);
        }
        __syncthreads();
        bf16x8 a[4], b[4];
#pragma unroll
        for (int i = 0; i < 4; i++) a[i] = *(const bf16x8*)&As[(wr + i * 16 + fr) * 32 + kg * 8];
#pragma unroll
        for (int j = 0; j < 4; j++) b[j] = *(const bf16x8*)&Bs[(wc + j * 16 + fr) * 32 + kg * 8];
#pragma unroll
        for (int i = 0; i < 4; i++)
#pragma unroll
            for (int j = 0; j < 4; j++)
                acc[i][j] = __builtin_amdgcn_mfma_f32_16x16x32_bf16(a[i], b[j], acc[i][j], 0, 0, 0);
        __syncthreads();
    }

    const int kg4 = kg * 4;
#pragma unroll
    for (int i = 0; i < 4; i++) {
        const int rb = m0 + wr + i * 16 + kg4;
#pragma unroll
        for (int j = 0; j < 4; j++) {
            const int c = n0 + wc + j * 16 + fr;
#pragma unroll
            for (int r = 0; r < 4; r++) {
                const int row = rb + r;
                if (row < M) {
                    float v = acc[i][j][r] + bias[c];
                    if (EPI == 1) {
                        outb[(size_t)row * ldo + c] = f2bf(gelu_(v));
                    } else if (EPI == 2) {
                        size_t o = (size_t)row * ldo + c;
                        outf[o] = xres[o] + gelu_(v);
                    } else {
                        outb[(size_t)pose[row] * ldo + c] = f2bf(v);
                    }
                }
            }
        }
    }
}

extern "C" void kernel_launch(void* const* d_in, const int* in_sizes, int n_in,
                              void* d_out, int out_size, void* d_ws, size_t ws_size,
                              hipStream_t stream) {
    const float* x = (const float*)d_in[0];
    const float* ea = (const float*)d_in[1];
    const float* gamma = (const float*)d_in[2];
    const float* beta = (const float*)d_in[3];
    const float* epsp = (const float*)d_in[4];
    const float* W_edge = (const float*)d_in[5];
    const float* b_edge = (const float*)d_in[6];
    const float* W1 = (const float*)d_in[7];
    const float* b1 = (const float*)d_in[8];
    const float* W2 = (const float*)d_in[9];
    const float* b2 = (const float*)d_in[10];
    const int* eidx = (const int*)d_in[11];
    float* out = (float*)d_out;
    const int N = in_sizes[0] / Df;
    const int E = in_sizes[1] / Df;
    const int* esrc = eidx;
    const int* edst = eidx + E;

    char* w = (char*)d_ws;
    size_t off_ = 0;
    auto alloc = [&](size_t bytes) { char* p = w + off_; off_ += (bytes + 255) & ~(size_t)255; return p; };
    float* stats = (float*)alloc(2 * Df * sizeof(float));
    float* coef = (float*)alloc(2 * Df * sizeof(float));
    unsigned short* hb = (unsigned short*)alloc((size_t)N * Df * 2);
    unsigned short* zb = (unsigned short*)alloc((size_t)N * Df * 2);
    unsigned short* tb = (unsigned short*)alloc((size_t)N * Hf * 2);
    unsigned short* WeT = (unsigned short*)alloc((size_t)Df * Df * 2);
    unsigned short* W1T = (unsigned short*)alloc((size_t)Df * Hf * 2);
    unsigned short* W2T = (unsigned short*)alloc((size_t)Hf * Df * 2);
    int* deg = (int*)alloc((size_t)(N + 1) * 4);      // reused as fill cursor
    int* offs = (int*)alloc((size_t)(N + 1) * 4);
    int* srcp = (int*)alloc((size_t)E * 4);
    int* pose = (int*)alloc((size_t)E * 4);
    int* sums = (int*)alloc(64 * 4);
    size_t msgl_bytes = (size_t)E * Df * 2;
    unsigned short* msgl;
    if (off_ + msgl_bytes <= ws_size) msgl = (unsigned short*)alloc(msgl_bytes);
    else msgl = (unsigned short*)d_out;   // dead until final GEMM writes it
    (void)n_in; (void)out_size;

    hipMemsetAsync(stats, 0, 2 * Df * sizeof(float), stream);
    hipMemsetAsync(deg, 0, (size_t)N * 4, stream);

    // BN + h
    bn_stats<<<1024, 192, 0, stream>>>(x, stats, N);
    bn_finalize<<<1, Df, 0, stream>>>(stats, gamma, beta, coef, N);
    int tot8 = N * Df / 8;
    h_kernel<<<(tot8 + 255) / 256, 256, 0, stream>>>(x, coef, hb, tot8);

    // weights
    wtrans<<<(Df * Df + 255) / 256, 256, 0, stream>>>(W_edge, WeT, Df, Df);
    wtrans<<<(Df * Hf + 255) / 256, 256, 0, stream>>>(W1, W1T, Df, Hf);
    wtrans<<<(Hf * Df + 255) / 256, 256, 0, stream>>>(W2, W2T, Hf, Df);

    // CSR by dst
    int nb = (N + SCAN_CH - 1) / SCAN_CH;
    degree_k<<<(E + 255) / 256, 256, 0, stream>>>(edst, deg, E);
    scan1<<<nb, 256, 0, stream>>>(deg, offs, sums, N);
    scan2<<<1, 1, 0, stream>>>(sums, nb);
    scan3<<<(N + 256) / 256, 256, 0, stream>>>(offs, sums, N, nb);
    hipMemcpyAsync(deg, offs, (size_t)N * 4, hipMemcpyDeviceToDevice, stream);
    fill_k<<<(E + 255) / 256, 256, 0, stream>>>(edst, esrc, deg, srcp, pose, E);

    // edge linear: msgl[pose[e]] = ea[e] @ We^T + b_edge  (bf16, CSR-ordered)
    dim3 ge(Df / 128, (E + 127) / 128);
    gemm_fused<3, false><<<ge, 256, 0, stream>>>(ea, WeT, b_edge, E, Df,
                                                 pose, msgl, nullptr, nullptr, Df);

    // gather-reduce -> z (bf16)
    aggregate<<<2048, 256, 0, stream>>>(msgl, hb, offs, srcp, epsp, zb, N);

    // MLP
    dim3 g1(Hf / 128, (N + 127) / 128);
    gemm_fused<1, true><<<g1, 256, 0, stream>>>(zb, W1T, b1, N, Df,
                                                nullptr, tb, nullptr, nullptr, Hf);
    dim3 g2(Df / 128, (N + 127) / 128);
    gemm_fused<2, true><<<g2, 256, 0, stream>>>(tb, W2T, b2, N, Hf,
                                                nullptr, nullptr, x, out, Df);
}

// Round 4
// 1084.817 us; speedup vs baseline: 1.3897x; 1.0270x over previous
//
#include <hip/hip_runtime.h>
#include <hip/hip_bf16.h>

#define Df 384
#define Hf 768
#define SCAN_CH 4096

typedef __bf16 bf16x8 __attribute__((ext_vector_type(8)));
typedef float f32x4 __attribute__((ext_vector_type(4)));

struct __attribute__((aligned(4))) U12 { unsigned int x, y, z; };

__device__ inline unsigned short f2bf(float f) {
    __hip_bfloat16 h = __float2bfloat16(f);
    return __builtin_bit_cast(unsigned short, h);
}
__device__ inline float bf2f(unsigned short u) {
    unsigned int v = ((unsigned int)u) << 16;
    return __builtin_bit_cast(float, v);
}
__device__ inline float lobf(unsigned int v) { return bf2f((unsigned short)(v & 0xffff)); }
__device__ inline float hibf(unsigned int v) { return bf2f((unsigned short)(v >> 16)); }
__device__ inline unsigned int pk2(float a, float b) {
    return (unsigned int)f2bf(a) | ((unsigned int)f2bf(b) << 16);
}
__device__ inline float gelu_(float v) {
    return 0.5f * v * (1.0f + erff(v * 0.70710678118654752f));
}
// direct global->LDS, 16B per lane; LDS dest is wave-uniform base + lane*16
__device__ inline void gload16(const void* g, void* l) {
    __builtin_amdgcn_global_load_lds(
        (const __attribute__((address_space(1))) unsigned int*)g,
        (__attribute__((address_space(3))) unsigned int*)l, 16, 0, 0);
}

// ---- BN column statistics: sum + sumsq per feature ----
__global__ void bn_stats(const float* __restrict__ x, float* __restrict__ stats, int N) {
    int t = threadIdx.x;                 // 192 threads
    int c4 = (t % 96) * 4;
    int rs = t / 96;
    float s0 = 0, s1 = 0, s2 = 0, s3 = 0, q0 = 0, q1 = 0, q2 = 0, q3 = 0;
    for (int r = blockIdx.x * 2 + rs; r < N; r += gridDim.x * 2) {
        float4 v = *(const float4*)(x + (size_t)r * Df + c4);
        s0 += v.x; s1 += v.y; s2 += v.z; s3 += v.w;
        q0 += v.x * v.x; q1 += v.y * v.y; q2 += v.z * v.z; q3 += v.w * v.w;
    }
    unsafeAtomicAdd(&stats[c4 + 0], s0);
    unsafeAtomicAdd(&stats[c4 + 1], s1);
    unsafeAtomicAdd(&stats[c4 + 2], s2);
    unsafeAtomicAdd(&stats[c4 + 3], s3);
    unsafeAtomicAdd(&stats[Df + c4 + 0], q0);
    unsafeAtomicAdd(&stats[Df + c4 + 1], q1);
    unsafeAtomicAdd(&stats[Df + c4 + 2], q2);
    unsafeAtomicAdd(&stats[Df + c4 + 3], q3);
}

__global__ void bn_finalize(const float* __restrict__ stats,
                            const float* __restrict__ gamma,
                            const float* __restrict__ beta,
                            float* __restrict__ coef, int N) {
    int c = threadIdx.x; // 384
    float invN = 1.0f / (float)N;
    float mu = stats[c] * invN;
    float var = stats[Df + c] * invN - mu * mu;
    float rs = rsqrtf(var + 1e-5f);
    float a = gamma[c] * rs;
    coef[c] = a;
    coef[Df + c] = beta[c] - mu * a;
}

// ---- h = x*a + b  ->  bf16 ----
__global__ void h_kernel(const float* __restrict__ x, const float* __restrict__ coef,
                         unsigned short* __restrict__ hb, int tot8) {
    int i = blockIdx.x * 256 + threadIdx.x;
    if (i >= tot8) return;
    size_t base = (size_t)i * 8;
    int c = (int)(base % Df);
    float4 x0 = *(const float4*)(x + base);
    float4 x1 = *(const float4*)(x + base + 4);
    const float* a = coef + c;
    const float* b = coef + Df + c;
    uint4 o;
    o.x = pk2(x0.x * a[0] + b[0], x0.y * a[1] + b[1]);
    o.y = pk2(x0.z * a[2] + b[2], x0.w * a[3] + b[3]);
    o.z = pk2(x1.x * a[4] + b[4], x1.y * a[5] + b[5]);
    o.w = pk2(x1.z * a[6] + b[6], x1.w * a[7] + b[7]);
    *(uint4*)(hb + base) = o;
}

// ---- weight transpose + cast: W[K][Nc] f32 -> Wt[Nc][K] bf16 ----
__global__ void wtrans(const float* __restrict__ Wsrc, unsigned short* __restrict__ Wdst,
                       int K, int Nc) {
    int idx = blockIdx.x * 256 + threadIdx.x;
    if (idx >= K * Nc) return;
    int k = idx / Nc, n = idx % Nc;
    Wdst[(size_t)n * K + k] = f2bf(Wsrc[idx]);
}

// ---- CSR build ----
__global__ void degree_k(const int* __restrict__ dst, int* __restrict__ deg, int E) {
    int e = blockIdx.x * 256 + threadIdx.x;
    if (e < E) atomicAdd(&deg[dst[e]], 1);
}

__global__ void scan1(const int* __restrict__ deg, int* __restrict__ off,
                      int* __restrict__ sums, int N) {
    __shared__ int ts[256];
    int t = threadIdx.x;
    int base = blockIdx.x * SCAN_CH + t * 16;
    int v[16];
    int s = 0;
    for (int j = 0; j < 16; j++) {
        int idx = base + j;
        int d = (idx < N) ? deg[idx] : 0;
        v[j] = s;
        s += d;
    }
    ts[t] = s;
    __syncthreads();
    for (int o = 1; o < 256; o <<= 1) {
        int add = (t >= o) ? ts[t - o] : 0;
        __syncthreads();
        ts[t] += add;
        __syncthreads();
    }
    int pre = t ? ts[t - 1] : 0;
    for (int j = 0; j < 16; j++) {
        int idx = base + j;
        if (idx < N) off[idx] = pre + v[j];
    }
    if (t == 255) sums[blockIdx.x] = ts[255];
}

__global__ void scan2(int* __restrict__ sums, int nb) {
    int acc = 0;
    for (int b = 0; b < nb; b++) { int v = sums[b]; sums[b] = acc; acc += v; }
    sums[nb] = acc;
}

__global__ void scan3(int* __restrict__ off, const int* __restrict__ sums, int N, int nb) {
    int idx = blockIdx.x * 256 + threadIdx.x;
    if (idx < N) off[idx] += sums[idx / SCAN_CH];
    else if (idx == N) off[N] = sums[nb];
}

// fill: pose[e] = CSR slot of edge e; srcp[slot] = src node of that edge
__global__ void fill_k(const int* __restrict__ dst, const int* __restrict__ src,
                       int* __restrict__ cursor, int* __restrict__ srcp,
                       int* __restrict__ pose, int E) {
    int e = blockIdx.x * 256 + threadIdx.x;
    if (e >= E) return;
    int pos = atomicAdd(&cursor[dst[e]], 1);
    srcp[pos] = src[e];
    pose[e] = pos;
}

// ---- gather-reduce: z[i] = (1+eps)*h[i] + sum_{p in [off[i],off[i+1])} relu(msgl[p] + h[srcp[p]]) ----
__global__ __launch_bounds__(256) void aggregate(
    const unsigned short* __restrict__ msgl, const unsigned short* __restrict__ hb,
    const int* __restrict__ off, const int* __restrict__ srcp,
    const float* __restrict__ epsp,
    unsigned short* __restrict__ zb, int N) {
    int lane = threadIdx.x & 63;
    int wid = threadIdx.x >> 6;
    int nwaves = gridDim.x * 4;
    float s1p = 1.0f + epsp[0];
    int loff = lane * 6;
    for (int i = blockIdx.x * 4 + wid; i < N; i += nwaves) {
        int o0 = off[i], o1 = off[i + 1];
        float a0 = 0, a1 = 0, a2 = 0, a3 = 0, a4 = 0, a5 = 0;
        for (int p = o0; p < o1; ++p) {
            int s = srcp[p];
            U12 mv = *(const U12*)(msgl + (size_t)p * Df + loff);
            U12 hv = *(const U12*)(hb + (size_t)s * Df + loff);
            a0 += fmaxf(lobf(mv.x) + lobf(hv.x), 0.f);
            a1 += fmaxf(hibf(mv.x) + hibf(hv.x), 0.f);
            a2 += fmaxf(lobf(mv.y) + lobf(hv.y), 0.f);
            a3 += fmaxf(hibf(mv.y) + hibf(hv.y), 0.f);
            a4 += fmaxf(lobf(mv.z) + lobf(hv.z), 0.f);
            a5 += fmaxf(hibf(mv.z) + hibf(hv.z), 0.f);
        }
        U12 hv = *(const U12*)(hb + (size_t)i * Df + loff);
        U12 o;
        o.x = pk2(s1p * lobf(hv.x) + a0, s1p * hibf(hv.x) + a1);
        o.y = pk2(s1p * lobf(hv.y) + a2, s1p * hibf(hv.y) + a3);
        o.z = pk2(s1p * lobf(hv.z) + a4, s1p * hibf(hv.z) + a5);
        *(U12*)(zb + (size_t)i * Df + loff) = o;
    }
}

// ---- fused GEMM: C = A @ Bt^T (+bias + epilogue) ----
// 1-D grid with m204 bijective XCD swizzle; within an XCD chunk the column
// block varies fastest so all col-blocks of one A-panel share that XCD's L2.
// Double-buffered LDS with global_load_lds prefetch (2-phase pipeline).
// EPI 1: out = bf16(gelu(acc + bias))
// EPI 2: out = xres + gelu(acc + bias)   (f32)
// EPI 3: out row permuted via pose: outb[pose[row]] = bf16(acc + bias)
template <int EPI, bool ABF16>
__global__ __launch_bounds__(256) void gemm_fused(
    const void* __restrict__ Ap, const unsigned short* __restrict__ Bt,
    const float* __restrict__ bias, int M, int K, int ncols,
    const int* __restrict__ pose,
    unsigned short* __restrict__ outb,
    const float* __restrict__ xres, float* __restrict__ outf, int ldo) {
    __shared__ __align__(16) unsigned short As[2][128 * 32];
    __shared__ __align__(16) unsigned short Bs[2][128 * 32];
    const int t = threadIdx.x;
    // m204 bijective XCD swizzle
    const int nwg = gridDim.x;
    const int orig = blockIdx.x;
    const int xcd = orig & 7;
    const int q = nwg >> 3, r = nwg & 7;
    const int wgid = (xcd < r ? xcd * (q + 1) : r * (q + 1) + (xcd - r) * q) + (orig >> 3);
    const int pp = wgid / ncols;
    const int m0 = pp * 128;
    const int n0 = (wgid - pp * ncols) * 128;

    const int lane = t & 63;
    const int wid = t >> 6;
    const int wr = (wid >> 1) << 6;
    const int wc = (wid & 1) << 6;
    const int fr = lane & 15;
    const int kg = lane >> 4;
    // gload lane coords: each wave stages 2x 1KB chunks (16 rows x 64B each)
    const int crow = lane >> 2;
    const int cseg = lane & 3;
    // f32 register-staging coords
    const int sr = t >> 1;
    const int sh = (t & 1) << 4;

    f32x4 acc[4][4];
#pragma unroll
    for (int i = 0; i < 4; i++)
#pragma unroll
        for (int j = 0; j < 4; j++) acc[i][j] = (f32x4){0.f, 0.f, 0.f, 0.f};

    const bool arok = (m0 + sr) < M;
    const size_t arowoff = (size_t)(m0 + sr) * K;
    const int NT = K >> 5;

    auto stageB = [&](int buf, int k0) {
#pragma unroll
        for (int h = 0; h < 2; h++) {
            const int rbase = wid * 32 + h * 16;
            gload16(Bt + (size_t)(n0 + rbase + crow) * K + k0 + cseg * 8,
                    &Bs[buf][rbase * 32]);
        }
    };
    auto stageA16 = [&](int buf, int k0) {
        const unsigned short* Ab = (const unsigned short*)Ap;
#pragma unroll
        for (int h = 0; h < 2; h++) {
            const int rbase = wid * 32 + h * 16;
            if (m0 + rbase + crow < M)
                gload16(Ab + (size_t)(m0 + rbase + crow) * K + k0 + cseg * 8,
                        &As[buf][rbase * 32]);
        }
    };

    // prologue: stage tile 0
    if (ABF16) {
        stageA16(0, 0);
    } else if (arok) {
        const float4* p = (const float4*)((const float*)Ap + arowoff + sh);
        float4 f0 = p[0], f1 = p[1], f2 = p[2], f3 = p[3];
        uint4 w0, w1;
        w0.x = pk2(f0.x, f0.y); w0.y = pk2(f0.z, f0.w);
        w0.z = pk2(f1.x, f1.y); w0.w = pk2(f1.z, f1.w);
        w1.x = pk2(f2.x, f2.y); w1.y = pk2(f2.z, f2.w);
        w1.z = pk2(f3.x, f3.y); w1.w = pk2(f3.z, f3.w);
        *(uint4*)&As[0][sr * 32 + sh] = w0;
        *(uint4*)&As[0][sr * 32 + sh + 8] = w1;
    }
    stageB(0, 0);
    __syncthreads();

    int cur = 0;
    for (int kt = 0; kt < NT; ++kt) {
        const int nxt = cur ^ 1;
        const bool more = (kt + 1) < NT;
        float4 f0, f1, f2, f3;
        if (more) {
            const int k0n = (kt + 1) * 32;
            if (ABF16) {
                stageA16(nxt, k0n);
            } else if (arok) {
                const float4* p = (const float4*)((const float*)Ap + arowoff + k0n + sh);
                f0 = p[0]; f1 = p[1]; f2 = p[2]; f3 = p[3];
            }
            stageB(nxt, k0n);
        }

        bf16x8 a[4], b[4];
#pragma unroll
        for (int i = 0; i < 4; i++) a[i] = *(const bf16x8*)&As[cur][(wr + i * 16 + fr) * 32 + kg * 8];
#pragma unroll
        for (int j = 0; j < 4; j++) b[j] = *(const bf16x8*)&Bs[cur][(wc + j * 16 + fr) * 32 + kg * 8];
#pragma unroll
        for (int i = 0; i < 4; i++)
#pragma unroll
            for (int j = 0; j < 4; j++)
                acc[i][j] = __builtin_amdgcn_mfma_f32_16x16x32_bf16(a[i], b[j], acc[i][j], 0, 0, 0);

        if (!ABF16 && more && arok) {
            uint4 w0, w1;
            w0.x = pk2(f0.x, f0.y); w0.y = pk2(f0.z, f0.w);
            w0.z = pk2(f1.x, f1.y); w0.w = pk2(f1.z, f1.w);
            w1.x = pk2(f2.x, f2.y); w1.y = pk2(f2.z, f2.w);
            w1.z = pk2(f3.x, f3.y); w1.w = pk2(f3.z, f3.w);
            *(uint4*)&As[nxt][sr * 32 + sh] = w0;
            *(uint4*)&As[nxt][sr * 32 + sh + 8] = w1;
        }
        __syncthreads();
        cur = nxt;
    }

    const int kg4 = kg * 4;
#pragma unroll
    for (int i = 0; i < 4; i++) {
        const int rb = m0 + wr + i * 16 + kg4;
#pragma unroll
        for (int j = 0; j < 4; j++) {
            const int c = n0 + wc + j * 16 + fr;
#pragma unroll
            for (int r = 0; r < 4; r++) {
                const int row = rb + r;
                if (row < M) {
                    float v = acc[i][j][r] + bias[c];
                    if (EPI == 1) {
                        outb[(size_t)row * ldo + c] = f2bf(gelu_(v));
                    } else if (EPI == 2) {
                        size_t o = (size_t)row * ldo + c;
                        outf[o] = xres[o] + gelu_(v);
                    } else {
                        outb[(size_t)pose[row] * ldo + c] = f2bf(v);
                    }
                }
            }
        }
    }
}

extern "C" void kernel_launch(void* const* d_in, const int* in_sizes, int n_in,
                              void* d_out, int out_size, void* d_ws, size_t ws_size,
                              hipStream_t stream) {
    const float* x = (const float*)d_in[0];
    const float* ea = (const float*)d_in[1];
    const float* gamma = (const float*)d_in[2];
    const float* beta = (const float*)d_in[3];
    const float* epsp = (const float*)d_in[4];
    const float* W_edge = (const float*)d_in[5];
    const float* b_edge = (const float*)d_in[6];
    const float* W1 = (const float*)d_in[7];
    const float* b1 = (const float*)d_in[8];
    const float* W2 = (const float*)d_in[9];
    const float* b2 = (const float*)d_in[10];
    const int* eidx = (const int*)d_in[11];
    float* out = (float*)d_out;
    const int N = in_sizes[0] / Df;
    const int E = in_sizes[1] / Df;
    const int* esrc = eidx;
    const int* edst = eidx + E;

    char* w = (char*)d_ws;
    size_t off_ = 0;
    auto alloc = [&](size_t bytes) { char* p = w + off_; off_ += (bytes + 255) & ~(size_t)255; return p; };
    float* stats = (float*)alloc(2 * Df * sizeof(float));
    float* coef = (float*)alloc(2 * Df * sizeof(float));
    unsigned short* hb = (unsigned short*)alloc((size_t)N * Df * 2);
    unsigned short* zb = (unsigned short*)alloc((size_t)N * Df * 2);
    unsigned short* tb = (unsigned short*)alloc((size_t)N * Hf * 2);
    unsigned short* WeT = (unsigned short*)alloc((size_t)Df * Df * 2);
    unsigned short* W1T = (unsigned short*)alloc((size_t)Df * Hf * 2);
    unsigned short* W2T = (unsigned short*)alloc((size_t)Hf * Df * 2);
    int* deg = (int*)alloc((size_t)(N + 1) * 4);      // reused as fill cursor
    int* offs = (int*)alloc((size_t)(N + 1) * 4);
    int* srcp = (int*)alloc((size_t)E * 4);
    int* pose = (int*)alloc((size_t)E * 4);
    int* sums = (int*)alloc(64 * 4);
    size_t msgl_bytes = (size_t)E * Df * 2;
    unsigned short* msgl;
    if (off_ + msgl_bytes <= ws_size) msgl = (unsigned short*)alloc(msgl_bytes);
    else msgl = (unsigned short*)d_out;   // dead until final GEMM writes it
    (void)n_in; (void)out_size;

    hipMemsetAsync(stats, 0, 2 * Df * sizeof(float), stream);
    hipMemsetAsync(deg, 0, (size_t)N * 4, stream);

    // BN + h
    bn_stats<<<1024, 192, 0, stream>>>(x, stats, N);
    bn_finalize<<<1, Df, 0, stream>>>(stats, gamma, beta, coef, N);
    int tot8 = N * Df / 8;
    h_kernel<<<(tot8 + 255) / 256, 256, 0, stream>>>(x, coef, hb, tot8);

    // weights
    wtrans<<<(Df * Df + 255) / 256, 256, 0, stream>>>(W_edge, WeT, Df, Df);
    wtrans<<<(Df * Hf + 255) / 256, 256, 0, stream>>>(W1, W1T, Df, Hf);
    wtrans<<<(Hf * Df + 255) / 256, 256, 0, stream>>>(W2, W2T, Hf, Df);

    // CSR by dst
    int nb = (N + SCAN_CH - 1) / SCAN_CH;
    degree_k<<<(E + 255) / 256, 256, 0, stream>>>(edst, deg, E);
    scan1<<<nb, 256, 0, stream>>>(deg, offs, sums, N);
    scan2<<<1, 1, 0, stream>>>(sums, nb);
    scan3<<<(N + 256) / 256, 256, 0, stream>>>(offs, sums, N, nb);
    hipMemcpyAsync(deg, offs, (size_t)N * 4, hipMemcpyDeviceToDevice, stream);
    fill_k<<<(E + 255) / 256, 256, 0, stream>>>(edst, esrc, deg, srcp, pose, E);

    // edge linear: msgl[pose[e]] = ea[e] @ We^T + b_edge  (bf16, CSR-ordered)
    int ep = (E + 127) / 128;
    gemm_fused<3, false><<<dim3(ep * (Df / 128)), 256, 0, stream>>>(
        ea, WeT, b_edge, E, Df, Df / 128, pose, msgl, nullptr, nullptr, Df);

    // gather-reduce -> z (bf16)
    aggregate<<<2048, 256, 0, stream>>>(msgl, hb, offs, srcp, epsp, zb, N);

    // MLP
    int np = (N + 127) / 128;
    gemm_fused<1, true><<<dim3(np * (Hf / 128)), 256, 0, stream>>>(
        zb, W1T, b1, N, Df, Hf / 128, nullptr, tb, nullptr, nullptr, Hf);
    gemm_fused<2, true><<<dim3(np * (Df / 128)), 256, 0, stream>>>(
        tb, W2T, b2, N, Hf, Df / 128, nullptr, nullptr, x, out, Df);
}